// Round 2
// baseline (1017.637 us; speedup 1.0000x reference)
//
#include <hip/hip_runtime.h>
#include <cmath>

#define BB 512
#define NN 2048
#define DD 128
#define SPLIT 4
#define NC (NN / SPLIT)  // 512 rows per block

// ---------------------------------------------------------------------------
// Kernel 1: per batch row b compute
//   Qp[e] = sum_d Q[b,d] * W1[e,d] + b1[e]
//   qt[b,d] = sum_e Qp[e] * W2[e,d]          (so alpha = K[b,n] . qt[b] + c)
//   c[b]  = sum_e Qp[e] * b2[e]
// ---------------------------------------------------------------------------
__global__ __launch_bounds__(128) void prep_kernel(
    const float* __restrict__ Q, const float* __restrict__ W1,
    const float* __restrict__ b1, const float* __restrict__ W2,
    const float* __restrict__ b2, float* __restrict__ qt,
    float* __restrict__ cvec) {
  const int b = blockIdx.x;
  const int t = threadIdx.x;  // 0..127
  __shared__ float Qs[DD];
  __shared__ float Qp[DD];
  __shared__ float red[DD];

  Qs[t] = Q[b * DD + t];
  __syncthreads();

  float acc = b1[t];
  const float4* w1row = (const float4*)(W1 + t * DD);
  #pragma unroll 8
  for (int i = 0; i < DD / 4; ++i) {
    float4 w = w1row[i];
    acc += Qs[4 * i + 0] * w.x + Qs[4 * i + 1] * w.y +
           Qs[4 * i + 2] * w.z + Qs[4 * i + 3] * w.w;
  }
  Qp[t] = acc;
  __syncthreads();

  float acc2 = 0.f;
  for (int e = 0; e < DD; ++e) acc2 += Qp[e] * W2[e * DD + t];
  qt[b * DD + t] = acc2;

  red[t] = Qp[t] * b2[t];
  __syncthreads();
  for (int s = 64; s > 0; s >>= 1) {
    if (t < s) red[t] += red[t + s];
    __syncthreads();
  }
  if (t == 0) cvec[b] = red[0];
}

// ---------------------------------------------------------------------------
// Kernel 2: grid (B, SPLIT). Single streaming pass over K AND V with
// group-local online softmax. Each 32-lane group handles 2 rows/iter with
// manual prefetch of the next iteration's K/V rows (loads guaranteed in
// flight across the shuffle/exp dependency chain). Raw logits go to LDS;
// epilogue merges the 8 groups (flash rescale), writes unnormalized
// p=exp(alpha-M) to out_w and the partial V-sum to part.
// ---------------------------------------------------------------------------
__global__ __launch_bounds__(256, 8) void attn_part_kernel(
    const float* __restrict__ K, const float* __restrict__ V,
    const float* __restrict__ adj, const float* __restrict__ qt,
    const float* __restrict__ cvec, float* __restrict__ out_w,
    float* __restrict__ part, float* __restrict__ mloc,
    float* __restrict__ sloc) {
  const int b = blockIdx.x;
  const int sc = blockIdx.y;          // chunk index 0..SPLIT-1
  const int n0 = sc * NC;
  const int tid = threadIdx.x;
  const int sub = tid & 31;           // lane within 32-group
  const int grp = tid >> 5;           // 0..7

  __shared__ float alpha[NC];         // raw logits, 2 KB
  __shared__ float redC[8 * DD];      // per-group partial V-sums, 4 KB
  __shared__ float gm[8];
  __shared__ float gs[8];

  const float4 qv = ((const float4*)(qt + (size_t)b * DD))[sub];
  const float cb = cvec[b];
  const float4* K4 = (const float4*)(K + ((size_t)b * NN + n0) * DD);
  const float4* V4 = (const float4*)(V + ((size_t)b * NN + n0) * DD);
  const float* adjb = adj + (size_t)b * NN + n0;

  float m = -1e30f;   // masked logits are exactly -1e30; see epilogue note
  float s = 0.f;
  float ax = 0.f, ay = 0.f, az = 0.f, aw = 0.f;

  const int NT = NC / 16;             // 16 rows per block-iter (8 grp x 2)
  int rb = grp * 2;

  // prefetch iteration 0
  float4 k0 = K4[(rb + 0) * 32 + sub];
  float4 k1 = K4[(rb + 1) * 32 + sub];
  float4 v0 = V4[(rb + 0) * 32 + sub];
  float4 v1 = V4[(rb + 1) * 32 + sub];
  float a0 = adjb[rb + 0];
  float a1 = adjb[rb + 1];

  for (int t = 0; t < NT; ++t) {
    const int rb2 = (t + 1 < NT) ? rb + 16 : rb;  // clamp keeps loads in-bounds
    // issue next-iteration loads BEFORE touching current data
    float4 nk0 = K4[(rb2 + 0) * 32 + sub];
    float4 nk1 = K4[(rb2 + 1) * 32 + sub];
    float4 nv0 = V4[(rb2 + 0) * 32 + sub];
    float4 nv1 = V4[(rb2 + 1) * 32 + sub];
    float na0 = adjb[rb2 + 0];
    float na1 = adjb[rb2 + 1];

    float p0 = k0.x * qv.x + k0.y * qv.y + k0.z * qv.z + k0.w * qv.w;
    float p1 = k1.x * qv.x + k1.y * qv.y + k1.z * qv.z + k1.w * qv.w;
    #pragma unroll
    for (int off = 16; off > 0; off >>= 1) {
      p0 += __shfl_xor(p0, off);
      p1 += __shfl_xor(p1, off);
    }
    const float al0 = p0 + cb - (1.0f - a0) * 1e30f;
    const float al1 = p1 + cb - (1.0f - a1) * 1e30f;
    if (sub == 0) {
      alpha[rb + 0] = al0;
      alpha[rb + 1] = al1;
    }

    // branchless online softmax update (scale == 1.0 exactly when no new max)
    const float mnew = fmaxf(m, fmaxf(al0, al1));
    const float scale = __expf(m - mnew);
    m = mnew;
    const float e0 = __expf(al0 - m);
    const float e1 = __expf(al1 - m);
    s = s * scale + (e0 + e1);
    ax = ax * scale + e0 * v0.x + e1 * v1.x;
    ay = ay * scale + e0 * v0.y + e1 * v1.y;
    az = az * scale + e0 * v0.z + e1 * v1.z;
    aw = aw * scale + e0 * v0.w + e1 * v1.w;

    k0 = nk0; k1 = nk1; v0 = nv0; v1 = nv1; a0 = na0; a1 = na1;
    rb = rb2;
  }
  // Note on masking: rows with adj==0 give al == -1e30 exactly (dot+c is
  // absorbed by fp32 rounding). If a group's prefix is all-masked, p=exp(0)=1
  // contributions are later annihilated by scale=exp(-1e30-real)=0; if an
  // entire group (or chunk) is masked, the cross-group/chunk rescale factor
  // exp(-1e30 - M) = 0 removes it — matching the reference softmax exactly
  // (including the degenerate all-masked => uniform case).

  if (sub == 0) { gm[grp] = m; gs[grp] = s; }
  float4 accv;
  accv.x = ax; accv.y = ay; accv.z = az; accv.w = aw;
  ((float4*)redC)[grp * 32 + sub] = accv;   // redC[grp*128 + sub*4 ..]
  __syncthreads();

  float M = gm[0];
  #pragma unroll
  for (int g = 1; g < 8; ++g) M = fmaxf(M, gm[g]);
  float fg[8];
  float S = 0.f;
  #pragma unroll
  for (int g = 0; g < 8; ++g) {
    fg[g] = __expf(gm[g] - M);
    S += gs[g] * fg[g];
  }

  if (tid == 0) {
    mloc[b * SPLIT + sc] = M;
    sloc[b * SPLIT + sc] = S;
  }

  if (tid < DD) {
    float ssum = 0.f;
    #pragma unroll
    for (int g = 0; g < 8; ++g) ssum += redC[g * DD + tid] * fg[g];
    part[((size_t)b * SPLIT + sc) * DD + tid] = ssum;
  }

  for (int i = tid; i < NC; i += 256)
    out_w[(size_t)b * NN + n0 + i] = __expf(alpha[i] - M);  // unnormalized
}

// ---------------------------------------------------------------------------
// Kernel 3: per b, merge SPLIT partials (flash-style rescale) and
// normalize out_w in place. ~10 MB total traffic.
// ---------------------------------------------------------------------------
__global__ __launch_bounds__(256) void combine_kernel(
    const float* __restrict__ part, const float* __restrict__ mloc,
    const float* __restrict__ sloc, float* __restrict__ out_w,
    float* __restrict__ out_s) {
  const int b = blockIdx.x;
  const int tid = threadIdx.x;

  float M = -INFINITY;
  #pragma unroll
  for (int sc = 0; sc < SPLIT; ++sc) M = fmaxf(M, mloc[b * SPLIT + sc]);
  float f[SPLIT];
  float T = 0.f;
  #pragma unroll
  for (int sc = 0; sc < SPLIT; ++sc) {
    float e = __expf(mloc[b * SPLIT + sc] - M);
    T += sloc[b * SPLIT + sc] * e;
    f[sc] = e;
  }
  const float inv = 1.0f / T;
  #pragma unroll
  for (int sc = 0; sc < SPLIT; ++sc) f[sc] *= inv;

  if (tid < DD) {
    float acc = 0.f;
    #pragma unroll
    for (int sc = 0; sc < SPLIT; ++sc)
      acc += part[((size_t)b * SPLIT + sc) * DD + tid] * f[sc];
    out_s[(size_t)b * DD + tid] = acc;
  }

  float4* w4 = (float4*)(out_w + (size_t)b * NN);
  for (int i = tid; i < NN / 4; i += 256) {   // 512 float4s, 2 iters
    const float fs = f[i >> 7];               // 128 float4s per chunk (NC/4)
    float4 v = w4[i];
    v.x *= fs; v.y *= fs; v.z *= fs; v.w *= fs;
    w4[i] = v;
  }
}

extern "C" void kernel_launch(void* const* d_in, const int* in_sizes, int n_in,
                              void* d_out, int out_size, void* d_ws, size_t ws_size,
                              hipStream_t stream) {
  const float* Q   = (const float*)d_in[0];
  const float* K   = (const float*)d_in[1];
  const float* V   = (const float*)d_in[2];
  const float* adj = (const float*)d_in[3];
  // d_in[4] = s_mask (unused by forward)
  const float* W1  = (const float*)d_in[5];
  const float* b1  = (const float*)d_in[6];
  const float* W2  = (const float*)d_in[7];
  const float* b2  = (const float*)d_in[8];

  float* out_w = (float*)d_out;                  // (B,1,N) flat
  float* out_s = out_w + (size_t)BB * NN;        // (B,D)

  float* qt   = (float*)d_ws;                    // B*D floats
  float* cvec = qt + (size_t)BB * DD;            // B floats
  float* part = cvec + BB;                       // B*SPLIT*D floats
  float* mloc = part + (size_t)BB * SPLIT * DD;  // B*SPLIT floats
  float* sloc = mloc + (size_t)BB * SPLIT;       // B*SPLIT floats

  prep_kernel<<<BB, DD, 0, stream>>>(Q, W1, b1, W2, b2, qt, cvec);
  dim3 grid2(BB, SPLIT);
  attn_part_kernel<<<grid2, 256, 0, stream>>>(K, V, adj, qt, cvec, out_w,
                                              part, mloc, sloc);
  combine_kernel<<<BB, 256, 0, stream>>>(part, mloc, sloc, out_w, out_s);
}